// Round 4
// baseline (447.073 us; speedup 1.0000x reference)
//
#include <hip/hip_runtime.h>

#define HW 3136
#define NPOS 100352.0f
#define NSLICE 32

typedef unsigned short ushortT;
typedef __attribute__((ext_vector_type(8))) short short8;
typedef __attribute__((ext_vector_type(4))) float floatx4;

__device__ inline float bf2f(ushortT u) {
    union { unsigned int i; float f; } v; v.i = ((unsigned int)u) << 16; return v.f;
}
__device__ inline ushortT f2bf(float f) {
    union { float f; unsigned int i; } v; v.f = f;
    unsigned int r = v.i + 0x7FFFu + ((v.i >> 16) & 1u);
    return (ushortT)(r >> 16);
}
// HW packed f32->bf16 (RNE), lo = S0, hi = S1. No builtin on gfx950 -> inline asm.
__device__ inline unsigned int cvtpk(float lo, float hi) {
    unsigned int r;
    asm("v_cvt_pk_bf16_f32 %0, %1, %2" : "=v"(r) : "v"(lo), "v"(hi));
    return r;
}

// async global->LDS, 16B per lane, wave-uniform LDS base + lane*16
__device__ inline void gl_lds16(const ushortT* g, ushortT* l) {
    __builtin_amdgcn_global_load_lds(
        (const __attribute__((address_space(1))) unsigned int*)g,
        (__attribute__((address_space(3))) unsigned int*)l, 16, 0, 0);
}

// ---------- prep: convert weights to bf16 (+ w3 reswizzle), zero stat partials ------
// partials layout (floats): p1[32][1024] | p2[32][1024] | p3[32][512]  = 81920 floats
__global__ __launch_bounds__(256) void prep_k(const float* __restrict__ w1,
                                              const float* __restrict__ w3,
                                              const float* __restrict__ wa,
                                              ushortT* __restrict__ w1b,
                                              ushortT* __restrict__ wab,
                                              ushortT* __restrict__ w3b,
                                              float* __restrict__ partials) {
    int i = blockIdx.x * 256 + threadIdx.x;
    if (i < 131072) { w1b[i] = f2bf(w1[i]); wab[i] = f2bf(wa[i]); }
    if (i < 81920) {
        // w3b[g][s 0..9][oc][ic], s==9 is a zero pad (dummy MFMA half)
        int ic = i & 15, oc = (i >> 4) & 15, rest = i >> 8;
        int s = rest % 10, g = rest / 10;
        w3b[i] = (s < 9) ? f2bf(w3[(((g * 16 + oc) * 16) + ic) * 9 + s]) : (ushortT)0;
        partials[i] = 0.f;
    }
}

// ---------- transpose x: [n][k 256][p 3136] f32 -> xb [n][p][k] bf16 ----------------
__global__ __launch_bounds__(256) void transx_k(const float* __restrict__ x,
                                                ushortT* __restrict__ xb) {
    __shared__ float tf[64 * 65];
    const int t = threadIdx.x;
    const int p0 = blockIdx.x * 64, k0 = blockIdx.y * 64, n = blockIdx.z;
#pragma unroll
    for (int i = 0; i < 16; i++) {
        int idx = t + i * 256;
        int k = idx >> 6, p = idx & 63;
        tf[k * 65 + p] = x[((size_t)n * 256 + k0 + k) * HW + p0 + p];
    }
    __syncthreads();
#pragma unroll
    for (int i = 0; i < 2; i++) {
        int idx = t + i * 256;
        int p = idx >> 3, kq = (idx & 7) * 8;
        short8 o;
#pragma unroll
        for (int j = 0; j < 8; j++) o[j] = (short)f2bf(tf[(kq + j) * 65 + p]);
        *(short8*)&xb[((size_t)n * HW + p0 + p) * 256 + k0 + kq] = o;
    }
}

// ---------- MFMA GEMM1: global_load_lds staging, BK=64, XOR-swizzled LDS ------------
__global__ __launch_bounds__(256) void gemm1_k(const ushortT* __restrict__ xb,
                                               const ushortT* __restrict__ w1b,
                                               const float* __restrict__ zpad,
                                               ushortT* __restrict__ t1,
                                               float* __restrict__ p1) {
    __shared__ ushortT As[128 * 64];
    __shared__ ushortT Bs[128 * 64];
    const int t = threadIdx.x;
    const int P0 = blockIdx.x * 128, C0 = blockIdx.y * 128, n = blockIdx.z;
    const int w = t >> 6, lane = t & 63;
    const int mh = (w >> 1) * 64, nh = (w & 1) * 64;
    const int l15 = lane & 15, quad = lane >> 4;

    const int srow = w * 32 + (lane >> 3);
    const int slin = lane & 7;

    const ushortT* agp[4];
    const ushortT* bgp[4];
#pragma unroll
    for (int i = 0; i < 4; i++) {
        int row = srow + i * 8;
        int sl = (slin ^ (row & 7)) * 8;          // pre-swizzled source slot
        agp[i] = w1b + (size_t)(C0 + row) * 256 + sl;
        int p = P0 + row;
        bgp[i] = (p < HW) ? xb + ((size_t)n * HW + p) * 256 + sl
                          : (const ushortT*)zpad;
    }
    ushortT* al = As + (w * 32) * 64;
    ushortT* bl = Bs + (w * 32) * 64;

    floatx4 acc[4][4];
#pragma unroll
    for (int a = 0; a < 4; a++)
#pragma unroll
        for (int b = 0; b < 4; b++)
#pragma unroll
            for (int e = 0; e < 4; e++) acc[a][b][e] = 0.f;

    for (int kb = 0; kb < 256; kb += 64) {
#pragma unroll
        for (int i = 0; i < 4; i++) gl_lds16(agp[i] + kb, al + i * 512);
#pragma unroll
        for (int i = 0; i < 4; i++) gl_lds16(bgp[i] + kb, bl + i * 512);
        __syncthreads();
        short8 af[2][4], bfv[2][4];
#pragma unroll
        for (int mt = 0; mt < 4; mt++) {
            int row = mh + mt * 16 + l15, rx = row & 7;
            af[0][mt] = *(const short8*)&As[row * 64 + ((quad ^ rx) * 8)];
            af[1][mt] = *(const short8*)&As[row * 64 + (((quad + 4) ^ rx) * 8)];
        }
#pragma unroll
        for (int nt = 0; nt < 4; nt++) {
            int row = nh + nt * 16 + l15, rx = row & 7;
            bfv[0][nt] = *(const short8*)&Bs[row * 64 + ((quad ^ rx) * 8)];
            bfv[1][nt] = *(const short8*)&Bs[row * 64 + (((quad + 4) ^ rx) * 8)];
        }
#pragma unroll
        for (int ks = 0; ks < 2; ks++)
#pragma unroll
            for (int mt = 0; mt < 4; mt++)
#pragma unroll
                for (int nt = 0; nt < 4; nt++)
                    acc[mt][nt] = __builtin_amdgcn_mfma_f32_16x16x32_bf16(
                        af[ks][mt], bfv[ks][nt], acc[mt][nt], 0, 0, 0);
        __syncthreads();
    }
#pragma unroll
    for (int mt = 0; mt < 4; mt++) {
        int c = C0 + mh + mt * 16 + quad * 4;
#pragma unroll
        for (int nt = 0; nt < 4; nt++) {
            int pp = P0 + nh + nt * 16 + l15;
            if (pp < HW) {
                ushort4 o;
                o.x = f2bf(acc[mt][nt][0]); o.y = f2bf(acc[mt][nt][1]);
                o.z = f2bf(acc[mt][nt][2]); o.w = f2bf(acc[mt][nt][3]);
                *(ushort4*)&t1[((size_t)n * HW + pp) * 512 + c] = o;
            }
        }
    }
    float* ps = p1 + ((blockIdx.x + blockIdx.z * 25) & (NSLICE - 1)) * 1024;
#pragma unroll
    for (int mt = 0; mt < 4; mt++) {
        int c = C0 + mh + mt * 16 + quad * 4;
#pragma unroll
        for (int e = 0; e < 4; e++) {
            float sv = acc[mt][0][e] + acc[mt][1][e] + acc[mt][2][e] + acc[mt][3][e];
            float qv = acc[mt][0][e] * acc[mt][0][e] + acc[mt][1][e] * acc[mt][1][e]
                     + acc[mt][2][e] * acc[mt][2][e] + acc[mt][3][e] * acc[mt][3][e];
            sv += __shfl_xor(sv, 1); qv += __shfl_xor(qv, 1);
            sv += __shfl_xor(sv, 2); qv += __shfl_xor(qv, 2);
            sv += __shfl_xor(sv, 4); qv += __shfl_xor(qv, 4);
            sv += __shfl_xor(sv, 8); qv += __shfl_xor(qv, 8);
            if (l15 == 0) {
                atomicAdd(&ps[c + e], sv);
                atomicAdd(&ps[512 + c + e], qv);
            }
        }
    }
}

// ---------- gconv: 2 groups/block (32ch), stride-58 tile (2-way max), BN1+ReLU ------
// tile[chq 0..3][row 0..9][col 0..57][8ch]; row stride 58 ≡ 2 (mod 8) -> fragment
// ds_read slot = (2*pr + pc + const) mod 8 = exactly 2 lanes/slot (free).
// LDS 37.4KB -> 4 blocks/CU (was 76KB -> 2); waves: w -> (group w>>1, rh w&1).
__global__ __launch_bounds__(256) void gconv_k(const ushortT* __restrict__ t1,
                                               const ushortT* __restrict__ w3b,
                                               const float* __restrict__ p1,
                                               const float* __restrict__ g1,
                                               const float* __restrict__ b1,
                                               ushortT* __restrict__ t2,
                                               float* __restrict__ p2) {
    __shared__ ushortT tile[4 * 580 * 8];
    __shared__ float scs[32], shs[32];
    const int t = threadIdx.x;
    const int rt = blockIdx.x, gg = blockIdx.y, n = blockIdx.z;  // gg 0..15
    const int r0 = rt * 8;

    if (t < 32) {
        int c = gg * 32 + t;
        float S = 0.f, Q = 0.f;
#pragma unroll
        for (int s = 0; s < NSLICE; s++) {
            S += p1[s * 1024 + c];
            Q += p1[s * 1024 + 512 + c];
        }
        float m = S * (1.f / NPOS);
        float var = Q * (1.f / NPOS) - m * m;
        float sc = g1[c] * rsqrtf(var + 1e-5f);
        scs[t] = sc; shs[t] = b1[c] - m * sc;
    }
    __syncthreads();

    const int chq = t & 3;
    float sc8[8], sh8[8];
#pragma unroll
    for (int j = 0; j < 8; j++) { sc8[j] = scs[chq * 8 + j]; sh8[j] = shs[chq * 8 + j]; }

    const ushortT* src = t1 + (size_t)n * HW * 512 + gg * 32 + chq * 8;
    for (int idx = t; idx < 2320; idx += 256) {
        int pos = idx >> 2;
        int row = pos / 58, col = pos - row * 58;   // row 0..9, col 0..57
        int ir = r0 - 1 + row, icl = col - 1;
        short8 o;
        if (ir >= 0 && ir < 56 && icl >= 0 && icl < 56) {
            short8 v = *(const short8*)&src[(size_t)(ir * 56 + icl) * 512];
            float f[8];
#pragma unroll
            for (int j = 0; j < 8; j++)
                f[j] = fmaxf(fmaf(sc8[j], bf2f((ushortT)v[j]), sh8[j]), 0.f);
            union { short8 s; unsigned int u[4]; } ov;
#pragma unroll
            for (int j = 0; j < 4; j++) ov.u[j] = cvtpk(f[2 * j], f[2 * j + 1]);
            o = ov.s;
        } else {
#pragma unroll
            for (int j = 0; j < 8; j++) o[j] = 0;
        }
        *(short8*)&tile[((chq * 580) + row * 58 + col) * 8] = o;
    }
    __syncthreads();

    const int w = t >> 6, lane = t & 63;
    const int l15 = lane & 15, quad = lane >> 4;
    const int qh = quad >> 1, ql = quad & 1;
    const int gl = w >> 1, rh = w & 1;         // wave -> (group-local, row-half)
    const int g = gg * 2 + gl;

    short8 af[5];
    int drv[5], dcv[5];
#pragma unroll
    for (int s = 0; s < 5; s++) {
        int shift = 2 * s + qh;
        af[s] = *(const short8*)&w3b[((g * 10 + shift) * 16 + l15) * 16 + ql * 8];
        if (shift == 9) shift = 8;             // dummy half: valid addr, zero weights
        drv[s] = shift / 3; dcv[s] = shift - drv[s] * 3;
    }

    const int pr = l15 >> 2, pc = l15 & 3;
    const int plane = (gl * 2 + ql) * 580;
    float s4[4] = {0.f, 0.f, 0.f, 0.f}, q4[4] = {0.f, 0.f, 0.f, 0.f};

    const int rbase = rh * 4 + pr;
    floatx4 acc[14];
#pragma unroll
    for (int ct = 0; ct < 14; ct++)
#pragma unroll
        for (int e = 0; e < 4; e++) acc[ct][e] = 0.f;

#pragma unroll
    for (int ct = 0; ct < 14; ct++) {
        int colb = ct * 4 + pc;
#pragma unroll
        for (int s = 0; s < 5; s++) {
            short8 bfv = *(const short8*)&tile[(plane + (rbase + drv[s]) * 58 + colb + dcv[s]) * 8];
            acc[ct] = __builtin_amdgcn_mfma_f32_16x16x32_bf16(af[s], bfv, acc[ct], 0, 0, 0);
        }
    }
#pragma unroll
    for (int ct = 0; ct < 14; ct++) {
        int pos = (r0 + rh * 4 + pr) * 56 + ct * 4 + pc;
        ushort4 o;
        o.x = f2bf(acc[ct][0]); o.y = f2bf(acc[ct][1]);
        o.z = f2bf(acc[ct][2]); o.w = f2bf(acc[ct][3]);
        *(ushort4*)&t2[((size_t)n * HW + pos) * 512 + g * 16 + quad * 4] = o;
#pragma unroll
        for (int e = 0; e < 4; e++) {
            float a = acc[ct][e];
            s4[e] += a; q4[e] += a * a;
        }
    }
    float* ps = p2 + ((blockIdx.x + blockIdx.z * 7) & (NSLICE - 1)) * 1024;
#pragma unroll
    for (int e = 0; e < 4; e++) {
        float sv = s4[e], qv = q4[e];
        sv += __shfl_xor(sv, 1); qv += __shfl_xor(qv, 1);
        sv += __shfl_xor(sv, 2); qv += __shfl_xor(qv, 2);
        sv += __shfl_xor(sv, 4); qv += __shfl_xor(qv, 4);
        sv += __shfl_xor(sv, 8); qv += __shfl_xor(qv, 8);
        if (l15 == 0) {
            atomicAdd(&ps[g * 16 + quad * 4 + e], sv);
            atomicAdd(&ps[512 + g * 16 + quad * 4 + e], qv);
        }
    }
}

// ---------- MFMA GEMM3: 512 thr, M=256 x N=128, BK=64, gl_lds A, reg-staged B -------
__global__ __launch_bounds__(512) void gemm3_k(const ushortT* __restrict__ t2,
                                               const ushortT* __restrict__ wab,
                                               const float* __restrict__ p2,
                                               const float* __restrict__ g3,
                                               const float* __restrict__ b3,
                                               ushortT* __restrict__ t3,
                                               float* __restrict__ p3) {
    __shared__ ushortT As[256 * 64];
    __shared__ ushortT Bs[128 * 64];
    __shared__ float2 scsh[512];
    const int t = threadIdx.x;
    const int P0 = blockIdx.x * 128, n = blockIdx.y;   // 25 blocks, tail OOB-guarded
    const int w = t >> 6, lane = t & 63;
    const int mh = (w >> 1) * 64, nh = (w & 1) * 64;   // 4 M-waves x 2 N-halves
    const int l15 = lane & 15, quad = lane >> 4;
    const int slin = t & 7;

    int brow[2]; const ushortT* bgp[2]; bool bval[2];
#pragma unroll
    for (int i = 0; i < 2; i++) {
        int row = (t >> 3) + i * 64;
        brow[i] = row;
        int p = P0 + row;
        bval[i] = (p < HW);
        int pe = bval[i] ? p : (HW - 1);               // clamp: valid addr, data unused
        bgp[i] = t2 + ((size_t)n * HW + pe) * 512 + slin * 8;
    }
    const int srow = w * 32 + (lane >> 3);
    const ushortT* agp[4];
#pragma unroll
    for (int i = 0; i < 4; i++) {
        int row = srow + i * 8;
        int sl = ((lane & 7) ^ (row & 7)) * 8;
        agp[i] = wab + (size_t)row * 512 + sl;
    }
    ushortT* al = As + (w * 32) * 64;

    short8 breg[2];
#pragma unroll
    for (int i = 0; i < 2; i++) breg[i] = *(const short8*)(bgp[i]);

    {
        int c = t;
        float S = 0.f, Q = 0.f;
#pragma unroll
        for (int s = 0; s < NSLICE; s++) {
            S += p2[s * 1024 + c];
            Q += p2[s * 1024 + 512 + c];
        }
        float m = S * (1.f / NPOS);
        float var = Q * (1.f / NPOS) - m * m;
        float sc = g3[c] * rsqrtf(var + 1e-5f);
        scsh[c] = make_float2(sc, b3[c] - m * sc);
    }
    __syncthreads();

    floatx4 acc[4][4];
#pragma unroll
    for (int a = 0; a < 4; a++)
#pragma unroll
        for (int b = 0; b < 4; b++)
#pragma unroll
            for (int e = 0; e < 4; e++) acc[a][b][e] = 0.f;

    for (int kb = 0; kb < 512; kb += 64) {
#pragma unroll
        for (int i = 0; i < 4; i++) gl_lds16(agp[i] + kb, al + i * 512);
#pragma unroll
        for (int i = 0; i < 2; i++) {
            int row = brow[i];
            ushortT* dst = Bs + row * 64 + ((slin ^ (row & 7)) * 8);
            if (bval[i]) {
                float f[8];
#pragma unroll
                for (int j = 0; j < 8; j++) {
                    float2 ss = scsh[kb + slin * 8 + j];
                    f[j] = fmaxf(fmaf(ss.x, bf2f((ushortT)breg[i][j]), ss.y), 0.f);
                }
                union { short8 s; unsigned int u[4]; } ov;
#pragma unroll
                for (int j = 0; j < 4; j++) ov.u[j] = cvtpk(f[2 * j], f[2 * j + 1]);
                *(short8*)dst = ov.s;
            } else {
                short8 z;
#pragma unroll
                for (int j = 0; j < 8; j++) z[j] = 0;   // zeros -> stats3 unaffected
                *(short8*)dst = z;
            }
        }
        __syncthreads();
        int kbn = (kb + 64 < 512) ? kb + 64 : 0;
#pragma unroll
        for (int i = 0; i < 2; i++) breg[i] = *(const short8*)(bgp[i] + kbn);
#pragma unroll
        for (int ks = 0; ks < 2; ks++) {
            short8 af[4], bfv[4];
#pragma unroll
            for (int mt = 0; mt < 4; mt++) {
                int row = mh + mt * 16 + l15, rx = row & 7;
                af[mt] = *(const short8*)&As[row * 64 + (((ks * 4 + quad) ^ rx) * 8)];
            }
#pragma unroll
            for (int nt = 0; nt < 4; nt++) {
                int row = nh + nt * 16 + l15, rx = row & 7;
                bfv[nt] = *(const short8*)&Bs[row * 64 + (((ks * 4 + quad) ^ rx) * 8)];
            }
#pragma unroll
            for (int mt = 0; mt < 4; mt++)
#pragma unroll
                for (int nt = 0; nt < 4; nt++)
                    acc[mt][nt] = __builtin_amdgcn_mfma_f32_16x16x32_bf16(
                        af[mt], bfv[nt], acc[mt][nt], 0, 0, 0);
        }
        __syncthreads();
    }
#pragma unroll
    for (int mt = 0; mt < 4; mt++) {
        int c = mh + mt * 16 + quad * 4;
#pragma unroll
        for (int nt = 0; nt < 4; nt++) {
            int pp = P0 + nh + nt * 16 + l15;
            if (pp < HW) {
                uint2 o;
                o.x = cvtpk(acc[mt][nt][0], acc[mt][nt][1]);
                o.y = cvtpk(acc[mt][nt][2], acc[mt][nt][3]);
                *(uint2*)&t3[((size_t)n * HW + pp) * 256 + c] = o;
            }
        }
    }
    float* ps = p3 + ((blockIdx.x + blockIdx.y * 25) & (NSLICE - 1)) * 512;
#pragma unroll
    for (int mt = 0; mt < 4; mt++) {
        int c = mh + mt * 16 + quad * 4;
#pragma unroll
        for (int e = 0; e < 4; e++) {
            float sv = acc[mt][0][e] + acc[mt][1][e] + acc[mt][2][e] + acc[mt][3][e];
            float qv = acc[mt][0][e] * acc[mt][0][e] + acc[mt][1][e] * acc[mt][1][e]
                     + acc[mt][2][e] * acc[mt][2][e] + acc[mt][3][e] * acc[mt][3][e];
            sv += __shfl_xor(sv, 1); qv += __shfl_xor(qv, 1);
            sv += __shfl_xor(sv, 2); qv += __shfl_xor(qv, 2);
            sv += __shfl_xor(sv, 4); qv += __shfl_xor(qv, 4);
            sv += __shfl_xor(sv, 8); qv += __shfl_xor(qv, 8);
            if (l15 == 0) {
                atomicAdd(&ps[c + e], sv);
                atomicAdd(&ps[256 + c + e], qv);
            }
        }
    }
}

// ---------- final: out[n][c][p] = relu(bn3(t3[n][p][c]) + x[n][c][p]) ---------------
__global__ __launch_bounds__(256) void final_k(const ushortT* __restrict__ t3,
                                               const float* __restrict__ x,
                                               const float* __restrict__ p3,
                                               const float* __restrict__ ga,
                                               const float* __restrict__ ba,
                                               float* __restrict__ out) {
    __shared__ float tf[64 * 65];
    __shared__ float scs[64], shs[64];
    const int t = threadIdx.x;
    const int p0 = blockIdx.x * 64, c0 = blockIdx.y * 64, n = blockIdx.z;
    if (t < 64) {
        int c = c0 + t;
        float S = 0.f, Q = 0.f;
#pragma unroll
        for (int s = 0; s < NSLICE; s++) {
            S += p3[s * 512 + c];
            Q += p3[s * 512 + 256 + c];
        }
        float m = S * (1.f / NPOS);
        float var = Q * (1.f / NPOS) - m * m;
        float sc = ga[c] * rsqrtf(var + 1e-5f);
        scs[t] = sc; shs[t] = ba[c] - m * sc;
    }
    __syncthreads();
#pragma unroll
    for (int i = 0; i < 4; i++) {
        int idx = t + i * 256;
        int p = idx >> 4, cq = (idx & 15) * 4;
        ushort4 v = *(const ushort4*)&t3[((size_t)n * HW + p0 + p) * 256 + c0 + cq];
        tf[(cq + 0) * 65 + p] = fmaf(scs[cq + 0], bf2f(v.x), shs[cq + 0]);
        tf[(cq + 1) * 65 + p] = fmaf(scs[cq + 1], bf2f(v.y), shs[cq + 1]);
        tf[(cq + 2) * 65 + p] = fmaf(scs[cq + 2], bf2f(v.z), shs[cq + 2]);
        tf[(cq + 3) * 65 + p] = fmaf(scs[cq + 3], bf2f(v.w), shs[cq + 3]);
    }
    __syncthreads();
#pragma unroll
    for (int i = 0; i < 4; i++) {
        int idx = t + i * 256;
        int c = idx >> 4, pq = (idx & 15) * 4;
        size_t off = ((size_t)n * 256 + c0 + c) * HW + p0 + pq;
        float4 xv = *(const float4*)&x[off];
        float4 o;
        o.x = fmaxf(tf[c * 65 + pq + 0] + xv.x, 0.f);
        o.y = fmaxf(tf[c * 65 + pq + 1] + xv.y, 0.f);
        o.z = fmaxf(tf[c * 65 + pq + 2] + xv.z, 0.f);
        o.w = fmaxf(tf[c * 65 + pq + 3] + xv.w, 0.f);
        *(float4*)&out[off] = o;
    }
}

extern "C" void kernel_launch(void* const* d_in, const int* in_sizes, int n_in,
                              void* d_out, int out_size, void* d_ws, size_t ws_size,
                              hipStream_t stream) {
    const float* x  = (const float*)d_in[0];
    const float* w1 = (const float*)d_in[1];
    const float* g1 = (const float*)d_in[2];
    const float* b1 = (const float*)d_in[3];
    const float* w3 = (const float*)d_in[4];
    const float* g3 = (const float*)d_in[5];
    const float* b3 = (const float*)d_in[6];
    const float* wa = (const float*)d_in[7];
    const float* ga = (const float*)d_in[8];
    const float* ba = (const float*)d_in[9];
    float* out = (float*)d_out;

    char* ws = (char*)d_ws;
    ushortT* t1 = (ushortT*)ws;
    ushortT* t3 = t1;
    ushortT* xb = (ushortT*)(ws + 102760448);
    ushortT* t2 = (ushortT*)(ws + 102760448);
    ushortT* w1b = (ushortT*)(ws + 205520896);
    ushortT* wab = (ushortT*)(ws + 205783040);
    ushortT* w3b = (ushortT*)(ws + 206045184);
    float* partials = (float*)(ws + 206209024);
    float* pt1 = partials;                 // 32 x 1024
    float* pt2 = partials + 32 * 1024;     // 32 x 1024
    float* pt3 = partials + 64 * 1024;     // 32 x 512 (zeroed by prep; zero-source
                                           // for gemm1 OOB lanes, then gemm3 output)

    prep_k<<<512, 256, 0, stream>>>(w1, w3, wa, w1b, wab, w3b, partials);
    transx_k<<<dim3(49, 4, 32), 256, 0, stream>>>(x, xb);
    gemm1_k<<<dim3(25, 4, 32), 256, 0, stream>>>(xb, w1b, pt3, t1, pt1);
    gconv_k<<<dim3(7, 16, 32), 256, 0, stream>>>(t1, w3b, pt1, g1, b1, t2, pt2);
    gemm3_k<<<dim3(25, 32), 512, 0, stream>>>(t2, wab, pt2, g3, b3, t3, pt3);
    final_k<<<dim3(49, 4, 32), 256, 0, stream>>>(t3, x, pt3, ga, ba, out);
}

// Round 5
// 438.249 us; speedup vs baseline: 1.0201x; 1.0201x over previous
//
#include <hip/hip_runtime.h>

#define HW 3136
#define NPOS 100352.0f
#define NSLICE 32

typedef unsigned short ushortT;
typedef __attribute__((ext_vector_type(8))) short short8;
typedef __attribute__((ext_vector_type(4))) float floatx4;

__device__ inline float bf2f(ushortT u) {
    union { unsigned int i; float f; } v; v.i = ((unsigned int)u) << 16; return v.f;
}
__device__ inline ushortT f2bf(float f) {
    union { float f; unsigned int i; } v; v.f = f;
    unsigned int r = v.i + 0x7FFFu + ((v.i >> 16) & 1u);
    return (ushortT)(r >> 16);
}
// HW packed f32->bf16 (RNE), lo = S0, hi = S1. No builtin on gfx950 -> inline asm.
__device__ inline unsigned int cvtpk(float lo, float hi) {
    unsigned int r;
    asm("v_cvt_pk_bf16_f32 %0, %1, %2" : "=v"(r) : "v"(lo), "v"(hi));
    return r;
}

// async global->LDS, 16B per lane, wave-uniform LDS base + lane*16
__device__ inline void gl_lds16(const ushortT* g, ushortT* l) {
    __builtin_amdgcn_global_load_lds(
        (const __attribute__((address_space(1))) unsigned int*)g,
        (__attribute__((address_space(3))) unsigned int*)l, 16, 0, 0);
}

// ---------- prep: convert weights to bf16 (+ w3 reswizzle), zero stat partials ------
// partials layout (floats): p1[32][1024] | p2[32][1024] | p3[32][512]  = 81920 floats
__global__ __launch_bounds__(256) void prep_k(const float* __restrict__ w1,
                                              const float* __restrict__ w3,
                                              const float* __restrict__ wa,
                                              ushortT* __restrict__ w1b,
                                              ushortT* __restrict__ wab,
                                              ushortT* __restrict__ w3b,
                                              float* __restrict__ partials) {
    int i = blockIdx.x * 256 + threadIdx.x;
    if (i < 131072) { w1b[i] = f2bf(w1[i]); wab[i] = f2bf(wa[i]); }
    if (i < 81920) {
        // w3b[g][s 0..9][oc][ic], s==9 is a zero pad (dummy MFMA half)
        int ic = i & 15, oc = (i >> 4) & 15, rest = i >> 8;
        int s = rest % 10, g = rest / 10;
        w3b[i] = (s < 9) ? f2bf(w3[(((g * 16 + oc) * 16) + ic) * 9 + s]) : (ushortT)0;
        partials[i] = 0.f;
    }
}

// ---------- transpose x: [n][k 256][p 3136] f32 -> xb [n][p][k] bf16 ----------------
__global__ __launch_bounds__(256) void transx_k(const float* __restrict__ x,
                                                ushortT* __restrict__ xb) {
    __shared__ float tf[64 * 65];
    const int t = threadIdx.x;
    const int p0 = blockIdx.x * 64, k0 = blockIdx.y * 64, n = blockIdx.z;
#pragma unroll
    for (int i = 0; i < 16; i++) {
        int idx = t + i * 256;
        int k = idx >> 6, p = idx & 63;
        tf[k * 65 + p] = x[((size_t)n * 256 + k0 + k) * HW + p0 + p];
    }
    __syncthreads();
#pragma unroll
    for (int i = 0; i < 2; i++) {
        int idx = t + i * 256;
        int p = idx >> 3, kq = (idx & 7) * 8;
        short8 o;
#pragma unroll
        for (int j = 0; j < 8; j++) o[j] = (short)f2bf(tf[(kq + j) * 65 + p]);
        *(short8*)&xb[((size_t)n * HW + p0 + p) * 256 + k0 + kq] = o;
    }
}

// ---------- MFMA GEMM1: global_load_lds staging, BK=64, XOR-swizzled LDS ------------
__global__ __launch_bounds__(256) void gemm1_k(const ushortT* __restrict__ xb,
                                               const ushortT* __restrict__ w1b,
                                               const float* __restrict__ zpad,
                                               ushortT* __restrict__ t1,
                                               float* __restrict__ p1) {
    __shared__ ushortT As[128 * 64];
    __shared__ ushortT Bs[128 * 64];
    const int t = threadIdx.x;
    const int P0 = blockIdx.x * 128, C0 = blockIdx.y * 128, n = blockIdx.z;
    const int w = t >> 6, lane = t & 63;
    const int mh = (w >> 1) * 64, nh = (w & 1) * 64;
    const int l15 = lane & 15, quad = lane >> 4;

    const int srow = w * 32 + (lane >> 3);
    const int slin = lane & 7;

    const ushortT* agp[4];
    const ushortT* bgp[4];
#pragma unroll
    for (int i = 0; i < 4; i++) {
        int row = srow + i * 8;
        int sl = (slin ^ (row & 7)) * 8;          // pre-swizzled source slot
        agp[i] = w1b + (size_t)(C0 + row) * 256 + sl;
        int p = P0 + row;
        bgp[i] = (p < HW) ? xb + ((size_t)n * HW + p) * 256 + sl
                          : (const ushortT*)zpad;
    }
    ushortT* al = As + (w * 32) * 64;
    ushortT* bl = Bs + (w * 32) * 64;

    floatx4 acc[4][4];
#pragma unroll
    for (int a = 0; a < 4; a++)
#pragma unroll
        for (int b = 0; b < 4; b++)
#pragma unroll
            for (int e = 0; e < 4; e++) acc[a][b][e] = 0.f;

    for (int kb = 0; kb < 256; kb += 64) {
#pragma unroll
        for (int i = 0; i < 4; i++) gl_lds16(agp[i] + kb, al + i * 512);
#pragma unroll
        for (int i = 0; i < 4; i++) gl_lds16(bgp[i] + kb, bl + i * 512);
        __syncthreads();
        short8 af[2][4], bfv[2][4];
#pragma unroll
        for (int mt = 0; mt < 4; mt++) {
            int row = mh + mt * 16 + l15, rx = row & 7;
            af[0][mt] = *(const short8*)&As[row * 64 + ((quad ^ rx) * 8)];
            af[1][mt] = *(const short8*)&As[row * 64 + (((quad + 4) ^ rx) * 8)];
        }
#pragma unroll
        for (int nt = 0; nt < 4; nt++) {
            int row = nh + nt * 16 + l15, rx = row & 7;
            bfv[0][nt] = *(const short8*)&Bs[row * 64 + ((quad ^ rx) * 8)];
            bfv[1][nt] = *(const short8*)&Bs[row * 64 + (((quad + 4) ^ rx) * 8)];
        }
#pragma unroll
        for (int ks = 0; ks < 2; ks++)
#pragma unroll
            for (int mt = 0; mt < 4; mt++)
#pragma unroll
                for (int nt = 0; nt < 4; nt++)
                    acc[mt][nt] = __builtin_amdgcn_mfma_f32_16x16x32_bf16(
                        af[ks][mt], bfv[ks][nt], acc[mt][nt], 0, 0, 0);
        __syncthreads();
    }
#pragma unroll
    for (int mt = 0; mt < 4; mt++) {
        int c = C0 + mh + mt * 16 + quad * 4;
#pragma unroll
        for (int nt = 0; nt < 4; nt++) {
            int pp = P0 + nh + nt * 16 + l15;
            if (pp < HW) {
                ushort4 o;
                o.x = f2bf(acc[mt][nt][0]); o.y = f2bf(acc[mt][nt][1]);
                o.z = f2bf(acc[mt][nt][2]); o.w = f2bf(acc[mt][nt][3]);
                *(ushort4*)&t1[((size_t)n * HW + pp) * 512 + c] = o;
            }
        }
    }
    float* ps = p1 + ((blockIdx.x + blockIdx.z * 25) & (NSLICE - 1)) * 1024;
#pragma unroll
    for (int mt = 0; mt < 4; mt++) {
        int c = C0 + mh + mt * 16 + quad * 4;
#pragma unroll
        for (int e = 0; e < 4; e++) {
            float sv = acc[mt][0][e] + acc[mt][1][e] + acc[mt][2][e] + acc[mt][3][e];
            float qv = acc[mt][0][e] * acc[mt][0][e] + acc[mt][1][e] * acc[mt][1][e]
                     + acc[mt][2][e] * acc[mt][2][e] + acc[mt][3][e] * acc[mt][3][e];
            sv += __shfl_xor(sv, 1); qv += __shfl_xor(qv, 1);
            sv += __shfl_xor(sv, 2); qv += __shfl_xor(qv, 2);
            sv += __shfl_xor(sv, 4); qv += __shfl_xor(qv, 4);
            sv += __shfl_xor(sv, 8); qv += __shfl_xor(qv, 8);
            if (l15 == 0) {
                atomicAdd(&ps[c + e], sv);
                atomicAdd(&ps[512 + c + e], qv);
            }
        }
    }
}

// ---------- gconv: 4 groups/block (64ch, 128B-coalesced), stride-58 tile, T14 -------
// Staging is issue-early/write-late: all 19 conditional short8 loads are issued into
// registers BEFORE any transform/ds_write, so ~19 loads/thread are in flight (vs ~1
// in the fused loop). Transform (BN1+ReLU+cvt_pk) then drains them in order.
// tile row stride 58 ≡ 2 (mod 8): fragment ds_read slot = 2*pr+pc+c mod 8 -> 2-way.
__global__ __launch_bounds__(256) void gconv_k(const ushortT* __restrict__ t1,
                                               const ushortT* __restrict__ w3b,
                                               const float* __restrict__ p1,
                                               const float* __restrict__ g1,
                                               const float* __restrict__ b1,
                                               ushortT* __restrict__ t2,
                                               float* __restrict__ p2) {
    __shared__ ushortT tile[8 * 580 * 8];   // 74.2 KB
    __shared__ float scs[64], shs[64];
    const int t = threadIdx.x;
    const int rt = blockIdx.x, gg = blockIdx.y, n = blockIdx.z;
    const int r0 = rt * 8;

    if (t < 64) {
        int c = gg * 64 + t;
        float S = 0.f, Q = 0.f;
#pragma unroll
        for (int s = 0; s < NSLICE; s++) {
            S += p1[s * 1024 + c];
            Q += p1[s * 1024 + 512 + c];
        }
        float m = S * (1.f / NPOS);
        float var = Q * (1.f / NPOS) - m * m;
        float sc = g1[c] * rsqrtf(var + 1e-5f);
        scs[t] = sc; shs[t] = b1[c] - m * sc;
    }
    __syncthreads();

    const int chq = t & 7;
    float sc8[8], sh8[8];
#pragma unroll
    for (int j = 0; j < 8; j++) { sc8[j] = scs[chq * 8 + j]; sh8[j] = shs[chq * 8 + j]; }

    const ushortT* src = t1 + (size_t)n * HW * 512 + gg * 64 + chq * 8;
    // ---- phase 1: issue all loads (independent -> deep vmcnt pipeline)
    short8 vreg[19];
#pragma unroll
    for (int i = 0; i < 19; i++) {
        int idx = t + i * 256;
        int pos = idx >> 3;
        int row = pos / 58, col = pos - row * 58;   // row 0..9, col 0..57
        int ir = r0 - 1 + row, icl = col - 1;
        if (idx < 4640 && ir >= 0 && ir < 56 && icl >= 0 && icl < 56)
            vreg[i] = *(const short8*)&src[(size_t)(ir * 56 + icl) * 512];
    }
    // ---- phase 2: transform + LDS write (drains loads in issue order)
#pragma unroll
    for (int i = 0; i < 19; i++) {
        int idx = t + i * 256;
        if (idx >= 4640) continue;
        int pos = idx >> 3;
        int row = pos / 58, col = pos - row * 58;
        int ir = r0 - 1 + row, icl = col - 1;
        short8 o;
        if (ir >= 0 && ir < 56 && icl >= 0 && icl < 56) {
            float f[8];
#pragma unroll
            for (int j = 0; j < 8; j++)
                f[j] = fmaxf(fmaf(sc8[j], bf2f((ushortT)vreg[i][j]), sh8[j]), 0.f);
            union { short8 s; unsigned int u[4]; } ov;
#pragma unroll
            for (int j = 0; j < 4; j++) ov.u[j] = cvtpk(f[2 * j], f[2 * j + 1]);
            o = ov.s;
        } else {
#pragma unroll
            for (int j = 0; j < 8; j++) o[j] = 0;
        }
        *(short8*)&tile[((chq * 580) + row * 58 + col) * 8] = o;
    }
    __syncthreads();

    const int w = t >> 6, lane = t & 63;
    const int l15 = lane & 15, quad = lane >> 4;
    const int qh = quad >> 1, ql = quad & 1;
    const int g = gg * 4 + w;                  // wave owns one group

    short8 af[5];
    int drv[5], dcv[5];
#pragma unroll
    for (int s = 0; s < 5; s++) {
        int shift = 2 * s + qh;
        af[s] = *(const short8*)&w3b[((g * 10 + shift) * 16 + l15) * 16 + ql * 8];
        if (shift == 9) shift = 8;             // dummy half: valid addr, zero weights
        drv[s] = shift / 3; dcv[s] = shift - drv[s] * 3;
    }

    const int pr = l15 >> 2, pc = l15 & 3;
    const int plane = (w * 2 + ql) * 580;
    float s4[4] = {0.f, 0.f, 0.f, 0.f}, q4[4] = {0.f, 0.f, 0.f, 0.f};

#pragma unroll
    for (int rh = 0; rh < 2; rh++) {
        const int rbase = rh * 4 + pr;
        floatx4 acc[14];
#pragma unroll
        for (int ct = 0; ct < 14; ct++)
#pragma unroll
            for (int e = 0; e < 4; e++) acc[ct][e] = 0.f;

#pragma unroll
        for (int ct = 0; ct < 14; ct++) {
            int colb = ct * 4 + pc;
#pragma unroll
            for (int s = 0; s < 5; s++) {
                short8 bfv = *(const short8*)&tile[(plane + (rbase + drv[s]) * 58 + colb + dcv[s]) * 8];
                acc[ct] = __builtin_amdgcn_mfma_f32_16x16x32_bf16(af[s], bfv, acc[ct], 0, 0, 0);
            }
        }
#pragma unroll
        for (int ct = 0; ct < 14; ct++) {
            int pos = (r0 + rh * 4 + pr) * 56 + ct * 4 + pc;
            ushort4 o;
            o.x = f2bf(acc[ct][0]); o.y = f2bf(acc[ct][1]);
            o.z = f2bf(acc[ct][2]); o.w = f2bf(acc[ct][3]);
            *(ushort4*)&t2[((size_t)n * HW + pos) * 512 + g * 16 + quad * 4] = o;
#pragma unroll
            for (int e = 0; e < 4; e++) {
                float a = acc[ct][e];
                s4[e] += a; q4[e] += a * a;
            }
        }
    }
    float* ps = p2 + ((blockIdx.x + blockIdx.z * 7) & (NSLICE - 1)) * 1024;
#pragma unroll
    for (int e = 0; e < 4; e++) {
        float sv = s4[e], qv = q4[e];
        sv += __shfl_xor(sv, 1); qv += __shfl_xor(qv, 1);
        sv += __shfl_xor(sv, 2); qv += __shfl_xor(qv, 2);
        sv += __shfl_xor(sv, 4); qv += __shfl_xor(qv, 4);
        sv += __shfl_xor(sv, 8); qv += __shfl_xor(qv, 8);
        if (l15 == 0) {
            atomicAdd(&ps[g * 16 + quad * 4 + e], sv);
            atomicAdd(&ps[512 + g * 16 + quad * 4 + e], qv);
        }
    }
}

// ---------- MFMA GEMM3: 512 thr, M=256 x N=128, BK=64, gl_lds A, reg-staged B -------
__global__ __launch_bounds__(512) void gemm3_k(const ushortT* __restrict__ t2,
                                               const ushortT* __restrict__ wab,
                                               const float* __restrict__ p2,
                                               const float* __restrict__ g3,
                                               const float* __restrict__ b3,
                                               ushortT* __restrict__ t3,
                                               float* __restrict__ p3) {
    __shared__ ushortT As[256 * 64];
    __shared__ ushortT Bs[128 * 64];
    __shared__ float2 scsh[512];
    const int t = threadIdx.x;
    const int P0 = blockIdx.x * 128, n = blockIdx.y;   // 25 blocks, tail OOB-guarded
    const int w = t >> 6, lane = t & 63;
    const int mh = (w >> 1) * 64, nh = (w & 1) * 64;   // 4 M-waves x 2 N-halves
    const int l15 = lane & 15, quad = lane >> 4;
    const int slin = t & 7;

    int brow[2]; const ushortT* bgp[2]; bool bval[2];
#pragma unroll
    for (int i = 0; i < 2; i++) {
        int row = (t >> 3) + i * 64;
        brow[i] = row;
        int p = P0 + row;
        bval[i] = (p < HW);
        int pe = bval[i] ? p : (HW - 1);               // clamp: valid addr, data unused
        bgp[i] = t2 + ((size_t)n * HW + pe) * 512 + slin * 8;
    }
    const int srow = w * 32 + (lane >> 3);
    const ushortT* agp[4];
#pragma unroll
    for (int i = 0; i < 4; i++) {
        int row = srow + i * 8;
        int sl = ((lane & 7) ^ (row & 7)) * 8;
        agp[i] = wab + (size_t)row * 512 + sl;
    }
    ushortT* al = As + (w * 32) * 64;

    short8 breg[2];
#pragma unroll
    for (int i = 0; i < 2; i++) breg[i] = *(const short8*)(bgp[i]);

    {
        int c = t;
        float S = 0.f, Q = 0.f;
#pragma unroll
        for (int s = 0; s < NSLICE; s++) {
            S += p2[s * 1024 + c];
            Q += p2[s * 1024 + 512 + c];
        }
        float m = S * (1.f / NPOS);
        float var = Q * (1.f / NPOS) - m * m;
        float sc = g3[c] * rsqrtf(var + 1e-5f);
        scsh[c] = make_float2(sc, b3[c] - m * sc);
    }
    __syncthreads();

    floatx4 acc[4][4];
#pragma unroll
    for (int a = 0; a < 4; a++)
#pragma unroll
        for (int b = 0; b < 4; b++)
#pragma unroll
            for (int e = 0; e < 4; e++) acc[a][b][e] = 0.f;

    for (int kb = 0; kb < 512; kb += 64) {
#pragma unroll
        for (int i = 0; i < 4; i++) gl_lds16(agp[i] + kb, al + i * 512);
#pragma unroll
        for (int i = 0; i < 2; i++) {
            int row = brow[i];
            ushortT* dst = Bs + row * 64 + ((slin ^ (row & 7)) * 8);
            if (bval[i]) {
                float f[8];
#pragma unroll
                for (int j = 0; j < 8; j++) {
                    float2 ss = scsh[kb + slin * 8 + j];
                    f[j] = fmaxf(fmaf(ss.x, bf2f((ushortT)breg[i][j]), ss.y), 0.f);
                }
                union { short8 s; unsigned int u[4]; } ov;
#pragma unroll
                for (int j = 0; j < 4; j++) ov.u[j] = cvtpk(f[2 * j], f[2 * j + 1]);
                *(short8*)dst = ov.s;
            } else {
                short8 z;
#pragma unroll
                for (int j = 0; j < 8; j++) z[j] = 0;   // zeros -> stats3 unaffected
                *(short8*)dst = z;
            }
        }
        __syncthreads();
        int kbn = (kb + 64 < 512) ? kb + 64 : 0;
#pragma unroll
        for (int i = 0; i < 2; i++) breg[i] = *(const short8*)(bgp[i] + kbn);
#pragma unroll
        for (int ks = 0; ks < 2; ks++) {
            short8 af[4], bfv[4];
#pragma unroll
            for (int mt = 0; mt < 4; mt++) {
                int row = mh + mt * 16 + l15, rx = row & 7;
                af[mt] = *(const short8*)&As[row * 64 + (((ks * 4 + quad) ^ rx) * 8)];
            }
#pragma unroll
            for (int nt = 0; nt < 4; nt++) {
                int row = nh + nt * 16 + l15, rx = row & 7;
                bfv[nt] = *(const short8*)&Bs[row * 64 + (((ks * 4 + quad) ^ rx) * 8)];
            }
#pragma unroll
            for (int mt = 0; mt < 4; mt++)
#pragma unroll
                for (int nt = 0; nt < 4; nt++)
                    acc[mt][nt] = __builtin_amdgcn_mfma_f32_16x16x32_bf16(
                        af[mt], bfv[nt], acc[mt][nt], 0, 0, 0);
        }
        __syncthreads();
    }
#pragma unroll
    for (int mt = 0; mt < 4; mt++) {
        int c = mh + mt * 16 + quad * 4;
#pragma unroll
        for (int nt = 0; nt < 4; nt++) {
            int pp = P0 + nh + nt * 16 + l15;
            if (pp < HW) {
                uint2 o;
                o.x = cvtpk(acc[mt][nt][0], acc[mt][nt][1]);
                o.y = cvtpk(acc[mt][nt][2], acc[mt][nt][3]);
                *(uint2*)&t3[((size_t)n * HW + pp) * 256 + c] = o;
            }
        }
    }
    float* ps = p3 + ((blockIdx.x + blockIdx.y * 25) & (NSLICE - 1)) * 512;
#pragma unroll
    for (int mt = 0; mt < 4; mt++) {
        int c = mh + mt * 16 + quad * 4;
#pragma unroll
        for (int e = 0; e < 4; e++) {
            float sv = acc[mt][0][e] + acc[mt][1][e] + acc[mt][2][e] + acc[mt][3][e];
            float qv = acc[mt][0][e] * acc[mt][0][e] + acc[mt][1][e] * acc[mt][1][e]
                     + acc[mt][2][e] * acc[mt][2][e] + acc[mt][3][e] * acc[mt][3][e];
            sv += __shfl_xor(sv, 1); qv += __shfl_xor(qv, 1);
            sv += __shfl_xor(sv, 2); qv += __shfl_xor(qv, 2);
            sv += __shfl_xor(sv, 4); qv += __shfl_xor(qv, 4);
            sv += __shfl_xor(sv, 8); qv += __shfl_xor(qv, 8);
            if (l15 == 0) {
                atomicAdd(&ps[c + e], sv);
                atomicAdd(&ps[256 + c + e], qv);
            }
        }
    }
}

// ---------- final: out[n][c][p] = relu(bn3(t3[n][p][c]) + x[n][c][p]) ---------------
__global__ __launch_bounds__(256) void final_k(const ushortT* __restrict__ t3,
                                               const float* __restrict__ x,
                                               const float* __restrict__ p3,
                                               const float* __restrict__ ga,
                                               const float* __restrict__ ba,
                                               float* __restrict__ out) {
    __shared__ float tf[64 * 65];
    __shared__ float scs[64], shs[64];
    const int t = threadIdx.x;
    const int p0 = blockIdx.x * 64, c0 = blockIdx.y * 64, n = blockIdx.z;
    if (t < 64) {
        int c = c0 + t;
        float S = 0.f, Q = 0.f;
#pragma unroll
        for (int s = 0; s < NSLICE; s++) {
            S += p3[s * 512 + c];
            Q += p3[s * 512 + 256 + c];
        }
        float m = S * (1.f / NPOS);
        float var = Q * (1.f / NPOS) - m * m;
        float sc = ga[c] * rsqrtf(var + 1e-5f);
        scs[t] = sc; shs[t] = ba[c] - m * sc;
    }
    __syncthreads();
#pragma unroll
    for (int i = 0; i < 4; i++) {
        int idx = t + i * 256;
        int p = idx >> 4, cq = (idx & 15) * 4;
        ushort4 v = *(const ushort4*)&t3[((size_t)n * HW + p0 + p) * 256 + c0 + cq];
        tf[(cq + 0) * 65 + p] = fmaf(scs[cq + 0], bf2f(v.x), shs[cq + 0]);
        tf[(cq + 1) * 65 + p] = fmaf(scs[cq + 1], bf2f(v.y), shs[cq + 1]);
        tf[(cq + 2) * 65 + p] = fmaf(scs[cq + 2], bf2f(v.z), shs[cq + 2]);
        tf[(cq + 3) * 65 + p] = fmaf(scs[cq + 3], bf2f(v.w), shs[cq + 3]);
    }
    __syncthreads();
#pragma unroll
    for (int i = 0; i < 4; i++) {
        int idx = t + i * 256;
        int c = idx >> 4, pq = (idx & 15) * 4;
        size_t off = ((size_t)n * 256 + c0 + c) * HW + p0 + pq;
        float4 xv = *(const float4*)&x[off];
        float4 o;
        o.x = fmaxf(tf[c * 65 + pq + 0] + xv.x, 0.f);
        o.y = fmaxf(tf[c * 65 + pq + 1] + xv.y, 0.f);
        o.z = fmaxf(tf[c * 65 + pq + 2] + xv.z, 0.f);
        o.w = fmaxf(tf[c * 65 + pq + 3] + xv.w, 0.f);
        *(float4*)&out[off] = o;
    }
}

extern "C" void kernel_launch(void* const* d_in, const int* in_sizes, int n_in,
                              void* d_out, int out_size, void* d_ws, size_t ws_size,
                              hipStream_t stream) {
    const float* x  = (const float*)d_in[0];
    const float* w1 = (const float*)d_in[1];
    const float* g1 = (const float*)d_in[2];
    const float* b1 = (const float*)d_in[3];
    const float* w3 = (const float*)d_in[4];
    const float* g3 = (const float*)d_in[5];
    const float* b3 = (const float*)d_in[6];
    const float* wa = (const float*)d_in[7];
    const float* ga = (const float*)d_in[8];
    const float* ba = (const float*)d_in[9];
    float* out = (float*)d_out;

    char* ws = (char*)d_ws;
    ushortT* t1 = (ushortT*)ws;
    ushortT* t3 = t1;
    ushortT* xb = (ushortT*)(ws + 102760448);
    ushortT* t2 = (ushortT*)(ws + 102760448);
    ushortT* w1b = (ushortT*)(ws + 205520896);
    ushortT* wab = (ushortT*)(ws + 205783040);
    ushortT* w3b = (ushortT*)(ws + 206045184);
    float* partials = (float*)(ws + 206209024);
    float* pt1 = partials;                 // 32 x 1024
    float* pt2 = partials + 32 * 1024;     // 32 x 1024
    float* pt3 = partials + 64 * 1024;     // 32 x 512 (zeroed by prep; zero-source
                                           // for gemm1 OOB lanes, then gemm3 output)

    prep_k<<<512, 256, 0, stream>>>(w1, w3, wa, w1b, wab, w3b, partials);
    transx_k<<<dim3(49, 4, 32), 256, 0, stream>>>(x, xb);
    gemm1_k<<<dim3(25, 4, 32), 256, 0, stream>>>(xb, w1b, pt3, t1, pt1);
    gconv_k<<<dim3(7, 8, 32), 256, 0, stream>>>(t1, w3b, pt1, g1, b1, t2, pt2);
    gemm3_k<<<dim3(25, 32), 512, 0, stream>>>(t2, wab, pt2, g3, b3, t3, pt3);
    final_k<<<dim3(49, 4, 32), 256, 0, stream>>>(t3, x, pt3, ga, ba, out);
}

// Round 6
// 424.116 us; speedup vs baseline: 1.0541x; 1.0333x over previous
//
#include <hip/hip_runtime.h>

#define HW 3136
#define NPOS 100352.0f
#define NSLICE 32

typedef unsigned short ushortT;
typedef __attribute__((ext_vector_type(8))) short short8;
typedef __attribute__((ext_vector_type(4))) float floatx4;

__device__ inline float bf2f(ushortT u) {
    union { unsigned int i; float f; } v; v.i = ((unsigned int)u) << 16; return v.f;
}
__device__ inline ushortT f2bf(float f) {
    union { float f; unsigned int i; } v; v.f = f;
    unsigned int r = v.i + 0x7FFFu + ((v.i >> 16) & 1u);
    return (ushortT)(r >> 16);
}
// HW packed f32->bf16 (RNE), lo = S0, hi = S1. No builtin on gfx950 -> inline asm.
__device__ inline unsigned int cvtpk(float lo, float hi) {
    unsigned int r;
    asm("v_cvt_pk_bf16_f32 %0, %1, %2" : "=v"(r) : "v"(lo), "v"(hi));
    return r;
}

// async global->LDS, 16B per lane, wave-uniform LDS base + lane*16
__device__ inline void gl_lds16(const ushortT* g, ushortT* l) {
    __builtin_amdgcn_global_load_lds(
        (const __attribute__((address_space(1))) unsigned int*)g,
        (__attribute__((address_space(3))) unsigned int*)l, 16, 0, 0);
}

// ---------- prep: convert weights to bf16 (+ w3 reswizzle), zero stat partials ------
// partials layout (floats): p1[32][1024] | p2[32][1024] | p3[32][512]  = 81920 floats
__global__ __launch_bounds__(256) void prep_k(const float* __restrict__ w1,
                                              const float* __restrict__ w3,
                                              const float* __restrict__ wa,
                                              ushortT* __restrict__ w1b,
                                              ushortT* __restrict__ wab,
                                              ushortT* __restrict__ w3b,
                                              float* __restrict__ partials) {
    int i = blockIdx.x * 256 + threadIdx.x;
    if (i < 131072) { w1b[i] = f2bf(w1[i]); wab[i] = f2bf(wa[i]); }
    if (i < 81920) {
        // w3b[g][s 0..9][oc][ic], s==9 is a zero pad (dummy MFMA half)
        int ic = i & 15, oc = (i >> 4) & 15, rest = i >> 8;
        int s = rest % 10, g = rest / 10;
        w3b[i] = (s < 9) ? f2bf(w3[(((g * 16 + oc) * 16) + ic) * 9 + s]) : (ushortT)0;
        partials[i] = 0.f;
    }
}

// ---------- transpose x: [n][k 256][p 3136] f32 -> xb [n][p][k] bf16 ----------------
__global__ __launch_bounds__(256) void transx_k(const float* __restrict__ x,
                                                ushortT* __restrict__ xb) {
    __shared__ float tf[64 * 65];
    const int t = threadIdx.x;
    const int p0 = blockIdx.x * 64, k0 = blockIdx.y * 64, n = blockIdx.z;
#pragma unroll
    for (int i = 0; i < 16; i++) {
        int idx = t + i * 256;
        int k = idx >> 6, p = idx & 63;
        tf[k * 65 + p] = x[((size_t)n * 256 + k0 + k) * HW + p0 + p];
    }
    __syncthreads();
#pragma unroll
    for (int i = 0; i < 2; i++) {
        int idx = t + i * 256;
        int p = idx >> 3, kq = (idx & 7) * 8;
        short8 o;
#pragma unroll
        for (int j = 0; j < 8; j++) o[j] = (short)f2bf(tf[(kq + j) * 65 + p]);
        *(short8*)&xb[((size_t)n * HW + p0 + p) * 256 + k0 + kq] = o;
    }
}

// ---------- MFMA GEMM1: 512 thr, M=128(C) x N=256(P), BK=64, gl_lds, XOR-swizzle ----
// 8 waves = 2 C-halves x 4 P-quarters, each wave 64x64 -> 32 MFMA per barrier pair;
// epilogue (16 frags) amortized over 128 MFMA/wave (2x better than 128x128/256thr).
__global__ __launch_bounds__(512) void gemm1_k(const ushortT* __restrict__ xb,
                                               const ushortT* __restrict__ w1b,
                                               const float* __restrict__ zpad,
                                               ushortT* __restrict__ t1,
                                               float* __restrict__ p1) {
    __shared__ ushortT As[128 * 64];
    __shared__ ushortT Bs[256 * 64];
    const int t = threadIdx.x;
    const int P0 = blockIdx.x * 256, C0 = blockIdx.y * 128, n = blockIdx.z;
    const int w = t >> 6, lane = t & 63;
    const int mh = (w >> 2) * 64, nh = (w & 3) * 64;
    const int l15 = lane & 15, quad = lane >> 4;

    const int lrow = lane >> 3;
    const int slin = lane & 7;

    // A: wave w owns rows [w*16, w*16+16); 2 instrs x 8 rows
    const ushortT* agp[2];
#pragma unroll
    for (int i = 0; i < 2; i++) {
        int row = w * 16 + lrow + i * 8;
        int sl = (slin ^ (row & 7)) * 8;          // pre-swizzled source slot
        agp[i] = w1b + (size_t)(C0 + row) * 256 + sl;
    }
    // B: wave w owns rows [w*32, w*32+32); 4 instrs x 8 rows
    const ushortT* bgp[4];
#pragma unroll
    for (int i = 0; i < 4; i++) {
        int row = w * 32 + lrow + i * 8;
        int sl = (slin ^ (row & 7)) * 8;
        int p = P0 + row;
        bgp[i] = (p < HW) ? xb + ((size_t)n * HW + p) * 256 + sl
                          : (const ushortT*)zpad;
    }
    ushortT* al = As + (w * 16) * 64;
    ushortT* bl = Bs + (w * 32) * 64;

    floatx4 acc[4][4];
#pragma unroll
    for (int a = 0; a < 4; a++)
#pragma unroll
        for (int b = 0; b < 4; b++)
#pragma unroll
            for (int e = 0; e < 4; e++) acc[a][b][e] = 0.f;

    for (int kb = 0; kb < 256; kb += 64) {
#pragma unroll
        for (int i = 0; i < 2; i++) gl_lds16(agp[i] + kb, al + i * 512);
#pragma unroll
        for (int i = 0; i < 4; i++) gl_lds16(bgp[i] + kb, bl + i * 512);
        __syncthreads();
#pragma unroll
        for (int ks = 0; ks < 2; ks++) {
            short8 af[4], bfv[4];
#pragma unroll
            for (int mt = 0; mt < 4; mt++) {
                int row = mh + mt * 16 + l15, rx = row & 7;
                af[mt] = *(const short8*)&As[row * 64 + (((ks * 4 + quad) ^ rx) * 8)];
            }
#pragma unroll
            for (int nt = 0; nt < 4; nt++) {
                int row = nh + nt * 16 + l15, rx = row & 7;
                bfv[nt] = *(const short8*)&Bs[row * 64 + (((ks * 4 + quad) ^ rx) * 8)];
            }
#pragma unroll
            for (int mt = 0; mt < 4; mt++)
#pragma unroll
                for (int nt = 0; nt < 4; nt++)
                    acc[mt][nt] = __builtin_amdgcn_mfma_f32_16x16x32_bf16(
                        af[mt], bfv[nt], acc[mt][nt], 0, 0, 0);
        }
        __syncthreads();
    }
#pragma unroll
    for (int mt = 0; mt < 4; mt++) {
        int c = C0 + mh + mt * 16 + quad * 4;
#pragma unroll
        for (int nt = 0; nt < 4; nt++) {
            int pp = P0 + nh + nt * 16 + l15;
            if (pp < HW) {
                ushort4 o;
                o.x = f2bf(acc[mt][nt][0]); o.y = f2bf(acc[mt][nt][1]);
                o.z = f2bf(acc[mt][nt][2]); o.w = f2bf(acc[mt][nt][3]);
                *(ushort4*)&t1[((size_t)n * HW + pp) * 512 + c] = o;
            }
        }
    }
    float* ps = p1 + ((blockIdx.x + blockIdx.z * 13) & (NSLICE - 1)) * 1024;
#pragma unroll
    for (int mt = 0; mt < 4; mt++) {
        int c = C0 + mh + mt * 16 + quad * 4;
#pragma unroll
        for (int e = 0; e < 4; e++) {
            float sv = acc[mt][0][e] + acc[mt][1][e] + acc[mt][2][e] + acc[mt][3][e];
            float qv = acc[mt][0][e] * acc[mt][0][e] + acc[mt][1][e] * acc[mt][1][e]
                     + acc[mt][2][e] * acc[mt][2][e] + acc[mt][3][e] * acc[mt][3][e];
            sv += __shfl_xor(sv, 1); qv += __shfl_xor(qv, 1);
            sv += __shfl_xor(sv, 2); qv += __shfl_xor(qv, 2);
            sv += __shfl_xor(sv, 4); qv += __shfl_xor(qv, 4);
            sv += __shfl_xor(sv, 8); qv += __shfl_xor(qv, 8);
            if (l15 == 0) {
                atomicAdd(&ps[c + e], sv);
                atomicAdd(&ps[512 + c + e], qv);
            }
        }
    }
}

// ---------- gconv: 4 groups/block (64ch, 128B-coalesced), stride-59 tile, T14 -------
// T14 issue-early/write-late staging (all 19 loads in flight before transform).
// Tile stride back to 59 (r3 layout): measured 5.05M conflicts vs 11.15M at 58.
__global__ __launch_bounds__(256) void gconv_k(const ushortT* __restrict__ t1,
                                               const ushortT* __restrict__ w3b,
                                               const float* __restrict__ p1,
                                               const float* __restrict__ g1,
                                               const float* __restrict__ b1,
                                               ushortT* __restrict__ t2,
                                               float* __restrict__ p2) {
    __shared__ ushortT tile[8 * 590 * 8];   // 75.5 KB
    __shared__ float scs[64], shs[64];
    const int t = threadIdx.x;
    const int rt = blockIdx.x, gg = blockIdx.y, n = blockIdx.z;
    const int r0 = rt * 8;

    if (t < 64) {
        int c = gg * 64 + t;
        float S = 0.f, Q = 0.f;
#pragma unroll
        for (int s = 0; s < NSLICE; s++) {
            S += p1[s * 1024 + c];
            Q += p1[s * 1024 + 512 + c];
        }
        float m = S * (1.f / NPOS);
        float var = Q * (1.f / NPOS) - m * m;
        float sc = g1[c] * rsqrtf(var + 1e-5f);
        scs[t] = sc; shs[t] = b1[c] - m * sc;
    }
    __syncthreads();

    const int chq = t & 7;
    float sc8[8], sh8[8];
#pragma unroll
    for (int j = 0; j < 8; j++) { sc8[j] = scs[chq * 8 + j]; sh8[j] = shs[chq * 8 + j]; }

    const ushortT* src = t1 + (size_t)n * HW * 512 + gg * 64 + chq * 8;
    // ---- phase 1: issue all loads (independent -> deep vmcnt pipeline)
    short8 vreg[19];
#pragma unroll
    for (int i = 0; i < 19; i++) {
        int idx = t + i * 256;
        int pos = idx >> 3;
        int row = pos / 58, col = pos - row * 58;   // row 0..9, col 0..57
        int ir = r0 - 1 + row, icl = col - 1;
        if (idx < 4640 && ir >= 0 && ir < 56 && icl >= 0 && icl < 56)
            vreg[i] = *(const short8*)&src[(size_t)(ir * 56 + icl) * 512];
    }
    // ---- phase 2: transform + LDS write (drains loads in issue order)
#pragma unroll
    for (int i = 0; i < 19; i++) {
        int idx = t + i * 256;
        if (idx >= 4640) continue;
        int pos = idx >> 3;
        int row = pos / 58, col = pos - row * 58;
        int ir = r0 - 1 + row, icl = col - 1;
        short8 o;
        if (ir >= 0 && ir < 56 && icl >= 0 && icl < 56) {
            float f[8];
#pragma unroll
            for (int j = 0; j < 8; j++)
                f[j] = fmaxf(fmaf(sc8[j], bf2f((ushortT)vreg[i][j]), sh8[j]), 0.f);
            union { short8 s; unsigned int u[4]; } ov;
#pragma unroll
            for (int j = 0; j < 4; j++) ov.u[j] = cvtpk(f[2 * j], f[2 * j + 1]);
            o = ov.s;
        } else {
#pragma unroll
            for (int j = 0; j < 8; j++) o[j] = 0;
        }
        *(short8*)&tile[((chq * 590) + row * 59 + col) * 8] = o;
    }
    __syncthreads();

    const int w = t >> 6, lane = t & 63;
    const int l15 = lane & 15, quad = lane >> 4;
    const int qh = quad >> 1, ql = quad & 1;
    const int g = gg * 4 + w;                  // wave owns one group

    short8 af[5];
    int drv[5], dcv[5];
#pragma unroll
    for (int s = 0; s < 5; s++) {
        int shift = 2 * s + qh;
        af[s] = *(const short8*)&w3b[((g * 10 + shift) * 16 + l15) * 16 + ql * 8];
        if (shift == 9) shift = 8;             // dummy half: valid addr, zero weights
        drv[s] = shift / 3; dcv[s] = shift - drv[s] * 3;
    }

    const int pr = l15 >> 2, pc = l15 & 3;
    const int plane = (w * 2 + ql) * 590;
    float s4[4] = {0.f, 0.f, 0.f, 0.f}, q4[4] = {0.f, 0.f, 0.f, 0.f};

#pragma unroll
    for (int rh = 0; rh < 2; rh++) {
        const int rbase = rh * 4 + pr;
        floatx4 acc[14];
#pragma unroll
        for (int ct = 0; ct < 14; ct++)
#pragma unroll
            for (int e = 0; e < 4; e++) acc[ct][e] = 0.f;

#pragma unroll
        for (int ct = 0; ct < 14; ct++) {
            int colb = ct * 4 + pc;
#pragma unroll
            for (int s = 0; s < 5; s++) {
                short8 bfv = *(const short8*)&tile[(plane + (rbase + drv[s]) * 59 + colb + dcv[s]) * 8];
                acc[ct] = __builtin_amdgcn_mfma_f32_16x16x32_bf16(af[s], bfv, acc[ct], 0, 0, 0);
            }
        }
#pragma unroll
        for (int ct = 0; ct < 14; ct++) {
            int pos = (r0 + rh * 4 + pr) * 56 + ct * 4 + pc;
            ushort4 o;
            o.x = f2bf(acc[ct][0]); o.y = f2bf(acc[ct][1]);
            o.z = f2bf(acc[ct][2]); o.w = f2bf(acc[ct][3]);
            *(ushort4*)&t2[((size_t)n * HW + pos) * 512 + g * 16 + quad * 4] = o;
#pragma unroll
            for (int e = 0; e < 4; e++) {
                float a = acc[ct][e];
                s4[e] += a; q4[e] += a * a;
            }
        }
    }
    float* ps = p2 + ((blockIdx.x + blockIdx.z * 7) & (NSLICE - 1)) * 1024;
#pragma unroll
    for (int e = 0; e < 4; e++) {
        float sv = s4[e], qv = q4[e];
        sv += __shfl_xor(sv, 1); qv += __shfl_xor(qv, 1);
        sv += __shfl_xor(sv, 2); qv += __shfl_xor(qv, 2);
        sv += __shfl_xor(sv, 4); qv += __shfl_xor(qv, 4);
        sv += __shfl_xor(sv, 8); qv += __shfl_xor(qv, 8);
        if (l15 == 0) {
            atomicAdd(&ps[g * 16 + quad * 4 + e], sv);
            atomicAdd(&ps[512 + g * 16 + quad * 4 + e], qv);
        }
    }
}

// ---------- MFMA GEMM3: 512 thr, M=256 x N=128, BK=64, gl_lds A, reg-staged B -------
__global__ __launch_bounds__(512) void gemm3_k(const ushortT* __restrict__ t2,
                                               const ushortT* __restrict__ wab,
                                               const float* __restrict__ p2,
                                               const float* __restrict__ g3,
                                               const float* __restrict__ b3,
                                               ushortT* __restrict__ t3,
                                               float* __restrict__ p3) {
    __shared__ ushortT As[256 * 64];
    __shared__ ushortT Bs[128 * 64];
    __shared__ float2 scsh[512];
    const int t = threadIdx.x;
    const int P0 = blockIdx.x * 128, n = blockIdx.y;   // 25 blocks, tail OOB-guarded
    const int w = t >> 6, lane = t & 63;
    const int mh = (w >> 1) * 64, nh = (w & 1) * 64;   // 4 M-waves x 2 N-halves
    const int l15 = lane & 15, quad = lane >> 4;
    const int slin = t & 7;

    int brow[2]; const ushortT* bgp[2]; bool bval[2];
#pragma unroll
    for (int i = 0; i < 2; i++) {
        int row = (t >> 3) + i * 64;
        brow[i] = row;
        int p = P0 + row;
        bval[i] = (p < HW);
        int pe = bval[i] ? p : (HW - 1);               // clamp: valid addr, data unused
        bgp[i] = t2 + ((size_t)n * HW + pe) * 512 + slin * 8;
    }
    const int srow = w * 32 + (lane >> 3);
    const ushortT* agp[4];
#pragma unroll
    for (int i = 0; i < 4; i++) {
        int row = srow + i * 8;
        int sl = ((lane & 7) ^ (row & 7)) * 8;
        agp[i] = wab + (size_t)row * 512 + sl;
    }
    ushortT* al = As + (w * 32) * 64;

    short8 breg[2];
#pragma unroll
    for (int i = 0; i < 2; i++) breg[i] = *(const short8*)(bgp[i]);

    {
        int c = t;
        float S = 0.f, Q = 0.f;
#pragma unroll
        for (int s = 0; s < NSLICE; s++) {
            S += p2[s * 1024 + c];
            Q += p2[s * 1024 + 512 + c];
        }
        float m = S * (1.f / NPOS);
        float var = Q * (1.f / NPOS) - m * m;
        float sc = g3[c] * rsqrtf(var + 1e-5f);
        scsh[c] = make_float2(sc, b3[c] - m * sc);
    }
    __syncthreads();

    floatx4 acc[4][4];
#pragma unroll
    for (int a = 0; a < 4; a++)
#pragma unroll
        for (int b = 0; b < 4; b++)
#pragma unroll
            for (int e = 0; e < 4; e++) acc[a][b][e] = 0.f;

    for (int kb = 0; kb < 512; kb += 64) {
#pragma unroll
        for (int i = 0; i < 4; i++) gl_lds16(agp[i] + kb, al + i * 512);
#pragma unroll
        for (int i = 0; i < 2; i++) {
            int row = brow[i];
            ushortT* dst = Bs + row * 64 + ((slin ^ (row & 7)) * 8);
            if (bval[i]) {
                float f[8];
#pragma unroll
                for (int j = 0; j < 8; j++) {
                    float2 ss = scsh[kb + slin * 8 + j];
                    f[j] = fmaxf(fmaf(ss.x, bf2f((ushortT)breg[i][j]), ss.y), 0.f);
                }
                union { short8 s; unsigned int u[4]; } ov;
#pragma unroll
                for (int j = 0; j < 4; j++) ov.u[j] = cvtpk(f[2 * j], f[2 * j + 1]);
                *(short8*)dst = ov.s;
            } else {
                short8 z;
#pragma unroll
                for (int j = 0; j < 8; j++) z[j] = 0;   // zeros -> stats3 unaffected
                *(short8*)dst = z;
            }
        }
        __syncthreads();
        int kbn = (kb + 64 < 512) ? kb + 64 : 0;
#pragma unroll
        for (int i = 0; i < 2; i++) breg[i] = *(const short8*)(bgp[i] + kbn);
#pragma unroll
        for (int ks = 0; ks < 2; ks++) {
            short8 af[4], bfv[4];
#pragma unroll
            for (int mt = 0; mt < 4; mt++) {
                int row = mh + mt * 16 + l15, rx = row & 7;
                af[mt] = *(const short8*)&As[row * 64 + (((ks * 4 + quad) ^ rx) * 8)];
            }
#pragma unroll
            for (int nt = 0; nt < 4; nt++) {
                int row = nh + nt * 16 + l15, rx = row & 7;
                bfv[nt] = *(const short8*)&Bs[row * 64 + (((ks * 4 + quad) ^ rx) * 8)];
            }
#pragma unroll
            for (int mt = 0; mt < 4; mt++)
#pragma unroll
                for (int nt = 0; nt < 4; nt++)
                    acc[mt][nt] = __builtin_amdgcn_mfma_f32_16x16x32_bf16(
                        af[mt], bfv[nt], acc[mt][nt], 0, 0, 0);
        }
        __syncthreads();
    }
#pragma unroll
    for (int mt = 0; mt < 4; mt++) {
        int c = mh + mt * 16 + quad * 4;
#pragma unroll
        for (int nt = 0; nt < 4; nt++) {
            int pp = P0 + nh + nt * 16 + l15;
            if (pp < HW) {
                uint2 o;
                o.x = cvtpk(acc[mt][nt][0], acc[mt][nt][1]);
                o.y = cvtpk(acc[mt][nt][2], acc[mt][nt][3]);
                *(uint2*)&t3[((size_t)n * HW + pp) * 256 + c] = o;
            }
        }
    }
    float* ps = p3 + ((blockIdx.x + blockIdx.y * 25) & (NSLICE - 1)) * 512;
#pragma unroll
    for (int mt = 0; mt < 4; mt++) {
        int c = mh + mt * 16 + quad * 4;
#pragma unroll
        for (int e = 0; e < 4; e++) {
            float sv = acc[mt][0][e] + acc[mt][1][e] + acc[mt][2][e] + acc[mt][3][e];
            float qv = acc[mt][0][e] * acc[mt][0][e] + acc[mt][1][e] * acc[mt][1][e]
                     + acc[mt][2][e] * acc[mt][2][e] + acc[mt][3][e] * acc[mt][3][e];
            sv += __shfl_xor(sv, 1); qv += __shfl_xor(qv, 1);
            sv += __shfl_xor(sv, 2); qv += __shfl_xor(qv, 2);
            sv += __shfl_xor(sv, 4); qv += __shfl_xor(qv, 4);
            sv += __shfl_xor(sv, 8); qv += __shfl_xor(qv, 8);
            if (l15 == 0) {
                atomicAdd(&ps[c + e], sv);
                atomicAdd(&ps[256 + c + e], qv);
            }
        }
    }
}

// ---------- final: out[n][c][p] = relu(bn3(t3[n][p][c]) + x[n][c][p]) ---------------
__global__ __launch_bounds__(256) void final_k(const ushortT* __restrict__ t3,
                                               const float* __restrict__ x,
                                               const float* __restrict__ p3,
                                               const float* __restrict__ ga,
                                               const float* __restrict__ ba,
                                               float* __restrict__ out) {
    __shared__ float tf[64 * 65];
    __shared__ float scs[64], shs[64];
    const int t = threadIdx.x;
    const int p0 = blockIdx.x * 64, c0 = blockIdx.y * 64, n = blockIdx.z;
    if (t < 64) {
        int c = c0 + t;
        float S = 0.f, Q = 0.f;
#pragma unroll
        for (int s = 0; s < NSLICE; s++) {
            S += p3[s * 512 + c];
            Q += p3[s * 512 + 256 + c];
        }
        float m = S * (1.f / NPOS);
        float var = Q * (1.f / NPOS) - m * m;
        float sc = ga[c] * rsqrtf(var + 1e-5f);
        scs[t] = sc; shs[t] = ba[c] - m * sc;
    }
    __syncthreads();
#pragma unroll
    for (int i = 0; i < 4; i++) {
        int idx = t + i * 256;
        int p = idx >> 4, cq = (idx & 15) * 4;
        ushort4 v = *(const ushort4*)&t3[((size_t)n * HW + p0 + p) * 256 + c0 + cq];
        tf[(cq + 0) * 65 + p] = fmaf(scs[cq + 0], bf2f(v.x), shs[cq + 0]);
        tf[(cq + 1) * 65 + p] = fmaf(scs[cq + 1], bf2f(v.y), shs[cq + 1]);
        tf[(cq + 2) * 65 + p] = fmaf(scs[cq + 2], bf2f(v.z), shs[cq + 2]);
        tf[(cq + 3) * 65 + p] = fmaf(scs[cq + 3], bf2f(v.w), shs[cq + 3]);
    }
    __syncthreads();
#pragma unroll
    for (int i = 0; i < 4; i++) {
        int idx = t + i * 256;
        int c = idx >> 4, pq = (idx & 15) * 4;
        size_t off = ((size_t)n * 256 + c0 + c) * HW + p0 + pq;
        float4 xv = *(const float4*)&x[off];
        float4 o;
        o.x = fmaxf(tf[c * 65 + pq + 0] + xv.x, 0.f);
        o.y = fmaxf(tf[c * 65 + pq + 1] + xv.y, 0.f);
        o.z = fmaxf(tf[c * 65 + pq + 2] + xv.z, 0.f);
        o.w = fmaxf(tf[c * 65 + pq + 3] + xv.w, 0.f);
        *(float4*)&out[off] = o;
    }
}

extern "C" void kernel_launch(void* const* d_in, const int* in_sizes, int n_in,
                              void* d_out, int out_size, void* d_ws, size_t ws_size,
                              hipStream_t stream) {
    const float* x  = (const float*)d_in[0];
    const float* w1 = (const float*)d_in[1];
    const float* g1 = (const float*)d_in[2];
    const float* b1 = (const float*)d_in[3];
    const float* w3 = (const float*)d_in[4];
    const float* g3 = (const float*)d_in[5];
    const float* b3 = (const float*)d_in[6];
    const float* wa = (const float*)d_in[7];
    const float* ga = (const float*)d_in[8];
    const float* ba = (const float*)d_in[9];
    float* out = (float*)d_out;

    char* ws = (char*)d_ws;
    ushortT* t1 = (ushortT*)ws;
    ushortT* t3 = t1;
    ushortT* xb = (ushortT*)(ws + 102760448);
    ushortT* t2 = (ushortT*)(ws + 102760448);
    ushortT* w1b = (ushortT*)(ws + 205520896);
    ushortT* wab = (ushortT*)(ws + 205783040);
    ushortT* w3b = (ushortT*)(ws + 206045184);
    float* partials = (float*)(ws + 206209024);
    float* pt1 = partials;                 // 32 x 1024
    float* pt2 = partials + 32 * 1024;     // 32 x 1024
    float* pt3 = partials + 64 * 1024;     // 32 x 512 (zeroed by prep; zero-source
                                           // for gemm1 OOB lanes, then gemm3 output)

    prep_k<<<512, 256, 0, stream>>>(w1, w3, wa, w1b, wab, w3b, partials);
    transx_k<<<dim3(49, 4, 32), 256, 0, stream>>>(x, xb);
    gemm1_k<<<dim3(13, 4, 32), 512, 0, stream>>>(xb, w1b, pt3, t1, pt1);
    gconv_k<<<dim3(7, 8, 32), 256, 0, stream>>>(t1, w3b, pt1, g1, b1, t2, pt2);
    gemm3_k<<<dim3(25, 32), 512, 0, stream>>>(t2, wab, pt2, g3, b3, t3, pt3);
    final_k<<<dim3(49, 4, 32), 256, 0, stream>>>(t3, x, pt3, ga, ba, out);
}